// Round 1
// baseline (2033.251 us; speedup 1.0000x reference)
//
#include <hip/hip_runtime.h>
#include <stdint.h>

#define HIDDEN 512
#define EMBED  256
#define VTGT   50257
#define VTGT_PAD 50304
#define TLEN   512
#define GATE3  1536
#define RK     32   // recurrence workgroups

typedef float f32x4 __attribute__((ext_vector_type(4)));
typedef unsigned int u32x4 __attribute__((ext_vector_type(4)));

__device__ __forceinline__ unsigned short f2bf(float f) {
  union { float f; unsigned u; } v; v.f = f;
  unsigned u = v.u;
  unsigned r = (u + 0x7FFFu + ((u >> 16) & 1u)) >> 16;
  return (unsigned short)r;
}

__device__ __forceinline__ float sigm(float x) {
  return 1.f / (1.f + __expf(-x));
}

// ---------- encoder: gi = Wih_e @ x_last + bih_e ----------
__global__ void kenc1(const int* source, const float* emb_e, const float* Wih_e,
                      const float* bih_e, float* genc) {
  __shared__ float xs[EMBED];
  int tid = threadIdx.x;
  int tok = source[511];
  if (tid < EMBED) xs[tid] = emb_e[(size_t)tok * EMBED + tid];
  __syncthreads();
  int j = blockIdx.x * 256 + tid;
  const float* w = Wih_e + (size_t)j * EMBED;
  float acc = bih_e[j];
  for (int k = 0; k < EMBED; k += 4) {
    float4 wv = *(const float4*)(w + k);
    acc += wv.x * xs[k] + wv.y * xs[k + 1] + wv.z * xs[k + 2] + wv.w * xs[k + 3];
  }
  genc[j] = acc;
}

// ---------- encoder gates: hseq[0] = (1-z)*n  (h0 = 0 so gh = bhh_e) ----------
__global__ void kenc2(const float* genc, const float* bhh_e, float* hseq) {
  int e = threadIdx.x; // 512 threads
  float r = sigm(genc[e] + bhh_e[e]);
  float z = sigm(genc[e + 512] + bhh_e[e + 512]);
  float n = tanhf(genc[e + 1024] + r * bhh_e[e + 1024]);
  hseq[e] = (1.f - z) * n;
}

// ---------- GI[t][j] = Wih_d @ relu(emb_d[tok_t]) + bih_d ----------
__global__ __launch_bounds__(256) void kgi(const int* target, const float* emb_d,
                                           const float* Wih_d, const float* bih_d,
                                           float* GI) {
  __shared__ float Xs[32][EMBED];
  int tid = threadIdx.x;
  int j0 = blockIdx.x * 128;
  int t0 = blockIdx.y * 32;
  for (int idx = tid; idx < 32 * EMBED; idx += 256) {
    int tt = idx >> 8, c = idx & 255;
    int t = t0 + tt;
    int tok = (t == 0) ? 0 : target[t - 1];
    float v = emb_d[(size_t)tok * EMBED + c];
    Xs[tt][c] = v > 0.f ? v : 0.f;
  }
  __syncthreads();
  int jl = tid & 127, tg = tid >> 7;
  int j = j0 + jl;
  const float* w = Wih_d + (size_t)j * EMBED;
  float acc[16];
#pragma unroll
  for (int i = 0; i < 16; ++i) acc[i] = 0.f;
  for (int k = 0; k < EMBED; k += 4) {
    float4 wv = *(const float4*)(w + k);
#pragma unroll
    for (int i = 0; i < 16; ++i) {
      int tl = tg * 16 + i;
      acc[i] += wv.x * Xs[tl][k] + wv.y * Xs[tl][k + 1] +
                wv.z * Xs[tl][k + 2] + wv.w * Xs[tl][k + 3];
    }
  }
  float b = bih_d[j];
#pragma unroll
  for (int i = 0; i < 16; ++i) {
    int t = t0 + tg * 16 + i;
    GI[(size_t)t * GATE3 + j] = acc[i] + b;
  }
}

// ---------- Wout f32 -> bf16 (padded rows zeroed) ----------
__global__ void kwout(const float* Wout, unsigned short* WB) {
  size_t npairs = (size_t)VTGT_PAD * HIDDEN / 2;
  size_t stride = (size_t)gridDim.x * blockDim.x;
  for (size_t p = (size_t)blockIdx.x * blockDim.x + threadIdx.x; p < npairs; p += stride) {
    size_t i = p * 2;
    int j = (int)(i / HIDDEN);
    float a = 0.f, b = 0.f;
    if (j < VTGT) { float2 v = *(const float2*)(Wout + i); a = v.x; b = v.y; }
    *(unsigned*)(WB + i) = (unsigned)f2bf(a) | ((unsigned)f2bf(b) << 16);
  }
}

// ---------- sequential GRU recurrence, 32 persistent WGs ----------
__global__ __launch_bounds__(256) void krec(const float* Whh, const float* bhh,
                                            const float* GI, float* hseq,
                                            unsigned* cnt) {
  int tid = threadIdx.x;
  int p = tid & 15;            // k-slice owner (lane bits 0..3)
  int e = blockIdx.x * 16 + (tid >> 4);
  int k0 = p * 32;
  // persistent weights in VGPRs: rows e, e+512, e+1024, cols k0..k0+31
  float wr[32], wz[32], wn[32];
  {
    const float* Wr = Whh + (size_t)e * HIDDEN + k0;
    const float* Wz = Whh + (size_t)(e + 512) * HIDDEN + k0;
    const float* Wn = Whh + (size_t)(e + 1024) * HIDDEN + k0;
#pragma unroll
    for (int i = 0; i < 32; i += 4) {
      *(float4*)&wr[i] = *(const float4*)(Wr + i);
      *(float4*)&wz[i] = *(const float4*)(Wz + i);
      *(float4*)&wn[i] = *(const float4*)(Wn + i);
    }
  }
  float br = bhh[e], bz = bhh[e + 512], bn = bhh[e + 1024];
  __shared__ float hb[16 * 36];   // padded stride 36: 16B aligned, 2-way banks (free)
  int hb_e = (e >> 5) * 36 + (e & 31);
  for (int t = 0; t < TLEN; ++t) {
    const float* hsrc = hseq + (size_t)t * HIDDEN;
    for (int g = tid; g < HIDDEN; g += 256) {
      float v = __hip_atomic_load((float*)(hsrc + g), __ATOMIC_RELAXED,
                                  __HIP_MEMORY_SCOPE_AGENT);
      hb[(g >> 5) * 36 + (g & 31)] = v;
    }
    __syncthreads();
    float pr = 0.f, pz = 0.f, pn = 0.f;
#pragma unroll
    for (int i = 0; i < 32; i += 4) {
      float4 hv = *(float4*)&hb[p * 36 + i];
      pr += wr[i] * hv.x + wr[i + 1] * hv.y + wr[i + 2] * hv.z + wr[i + 3] * hv.w;
      pz += wz[i] * hv.x + wz[i + 1] * hv.y + wz[i + 2] * hv.z + wz[i + 3] * hv.w;
      pn += wn[i] * hv.x + wn[i + 1] * hv.y + wn[i + 2] * hv.z + wn[i + 3] * hv.w;
    }
#pragma unroll
    for (int m = 1; m < 16; m <<= 1) {
      pr += __shfl_xor(pr, m, 64);
      pz += __shfl_xor(pz, m, 64);
      pn += __shfl_xor(pn, m, 64);
    }
    if (p == 0) {
      const float* git = GI + (size_t)t * GATE3;
      float gr = git[e] + pr + br;
      float gz = git[e + 512] + pz + bz;
      float r = sigm(gr);
      float z = sigm(gz);
      float n = tanhf(git[e + 1024] + r * (pn + bn));
      float hold = hb[hb_e];
      float hnew = (1.f - z) * n + z * hold;
      __hip_atomic_store(hseq + (size_t)(t + 1) * HIDDEN + e, hnew,
                         __ATOMIC_RELAXED, __HIP_MEMORY_SCOPE_AGENT);
    }
    __syncthreads();            // all WG stores drained (s_waitcnt before s_barrier)
    if (tid == 0) {
      __hip_atomic_fetch_add(cnt, 1u, __ATOMIC_RELEASE, __HIP_MEMORY_SCOPE_AGENT);
      unsigned tgt = (unsigned)RK * (unsigned)(t + 1);
      while (__hip_atomic_load(cnt, __ATOMIC_ACQUIRE, __HIP_MEMORY_SCOPE_AGENT) < tgt) {}
    }
    __syncthreads();
  }
}

// ---------- h2 f32 -> bf16 ----------
__global__ void khb(const float* hseq, unsigned short* HB) {
  size_t idx = (size_t)blockIdx.x * blockDim.x + threadIdx.x; // 0..131071 pairs
  float2 v = *(const float2*)(hseq + HIDDEN + idx * 2);
  *(unsigned*)(HB + idx * 2) = (unsigned)f2bf(v.x) | ((unsigned)f2bf(v.y) << 16);
}

// ---------- logits = HB @ WB^T + bout  (bf16 MFMA) ----------
__global__ __launch_bounds__(256) void kgemm(const unsigned short* HB,
                                             const unsigned short* WB,
                                             const float* bout, float* out) {
  __shared__ unsigned short As[64 * 264]; // 64 rows x (256+8 pad) bf16, per K-half
  int tid = threadIdx.x;
  int lane = tid & 63, w = tid >> 6;
  int j0 = blockIdx.x * 64;
  int t0 = blockIdx.y * 64;
  int jl = lane & 15, kq = lane >> 4;
  int j = j0 + w * 16 + jl;
  f32x4 acc[4];
#pragma unroll
  for (int i = 0; i < 4; ++i) acc[i] = (f32x4)(0.f);
  for (int kh = 0; kh < 2; ++kh) {
    __syncthreads();
    // stage A half-tile: rows t0..t0+63, k in [kh*256, kh*256+256)
#pragma unroll
    for (int i = 0; i < 8; ++i) {
      int c = tid + 256 * i;            // 0..2047 chunks of 8 bf16
      int row = c >> 5, off = (c & 31) * 8;
      u32x4 v = *(const u32x4*)(HB + (size_t)(t0 + row) * HIDDEN + kh * 256 + off);
      *(u32x4*)(As + row * 264 + off) = v;
    }
    __syncthreads();
    const unsigned short* Bp = WB + (size_t)j * HIDDEN + kh * 256 + kq * 8;
#pragma unroll
    for (int ks = 0; ks < 8; ++ks) {
      u32x4 bfrag = *(const u32x4*)(Bp + ks * 32);
#pragma unroll
      for (int tq = 0; tq < 4; ++tq) {
        u32x4 afrag = *(const u32x4*)(As + (tq * 16 + jl) * 264 + ks * 32 + kq * 8);
        asm volatile("v_mfma_f32_16x16x32_bf16 %0, %1, %2, %0"
                     : "+v"(acc[tq])
                     : "v"(afrag), "v"(bfrag));
      }
    }
  }
  asm volatile("s_nop 7\n\ts_nop 7\n\ts_nop 7" ::);
  bool jok = j < VTGT;
  float bj = jok ? bout[j] : 0.f;
#pragma unroll
  for (int tq = 0; tq < 4; ++tq) {
#pragma unroll
    for (int r = 0; r < 4; ++r) {
      int t = t0 + tq * 16 + kq * 4 + r;   // D: row=(lane>>4)*4+reg, col=lane&15
      if (jok) out[(size_t)t * VTGT + j] = acc[tq][r] + bj;
    }
  }
}

// ---------- per-row logsumexp over d_out ----------
__global__ void klse(const float* out, float* lse) {
  int t = blockIdx.x, tid = threadIdx.x;
  const float* row = out + (size_t)t * VTGT;
  float m = -INFINITY, s = 0.f;
  for (int jj = tid; jj < VTGT; jj += 1024) {
    float x = row[jj];
    if (x > m) { s = s * __expf(m - x) + 1.f; m = x; }
    else s += __expf(x - m);
  }
#pragma unroll
  for (int d = 1; d < 64; d <<= 1) {
    float mo = __shfl_xor(m, d, 64), so = __shfl_xor(s, d, 64);
    float mn = fmaxf(m, mo);
    s = s * __expf(m - mn) + so * __expf(mo - mn);
    m = mn;
  }
  __shared__ float sm[16], sv[16];
  if ((tid & 63) == 0) { sm[tid >> 6] = m; sv[tid >> 6] = s; }
  __syncthreads();
  if (tid == 0) {
    for (int q = 1; q < 16; ++q) {
      float mo = sm[q], so = sv[q];
      float mn = fmaxf(m, mo);
      s = s * __expf(m - mn) + so * __expf(mo - mn);
      m = mn;
    }
    lse[t] = m + logf(s);
  }
}

// ---------- logp = logits - lse[t], in place ----------
__global__ void ksub(float* out, const float* lse) {
  int t = blockIdx.x;
  float l = lse[t];
  float* row = out + (size_t)t * VTGT;
  for (int jj = threadIdx.x; jj < VTGT; jj += 1024) row[jj] -= l;
}

extern "C" void kernel_launch(void* const* d_in, const int* in_sizes, int n_in,
                              void* d_out, int out_size, void* d_ws, size_t ws_size,
                              hipStream_t stream) {
  const int*   source = (const int*)d_in[0];
  const int*   target = (const int*)d_in[1];
  const float* emb_e  = (const float*)d_in[2];
  const float* Wih_e  = (const float*)d_in[3];
  // d_in[4] = Whh_e: unused (h0 == 0)
  const float* bih_e  = (const float*)d_in[5];
  const float* bhh_e  = (const float*)d_in[6];
  const float* emb_d  = (const float*)d_in[7];
  const float* Wih_d  = (const float*)d_in[8];
  const float* Whh_d  = (const float*)d_in[9];
  const float* bih_d  = (const float*)d_in[10];
  const float* bhh_d  = (const float*)d_in[11];
  const float* Wout   = (const float*)d_in[12];
  const float* bout   = (const float*)d_in[13];
  float* out = (float*)d_out;
  char* ws = (char*)d_ws;

  // ws layout (bytes)
  unsigned*       cnt  = (unsigned*)(ws + 0);                 //      256
  float*          GI   = (float*)(ws + 256);                  // 3,145,728
  float*          hseq = (float*)(ws + 3145984);              // 1,050,624 (513 x 512)
  float*          lse  = (float*)(ws + 4196608);              //     2,048
  float*          genc = (float*)(ws + 4198656);              //     6,144
  unsigned short* WB   = (unsigned short*)(ws + 4204800);     // 51,511,296 (50304 x 512 bf16)
  unsigned short* HB   = (unsigned short*)(ws + 55716096);    //   524,288  (512 x 512 bf16)
  // total ws use ~56.3 MB

  hipMemsetAsync(cnt, 0, 256, stream);
  kenc1<<<6, 256, 0, stream>>>(source, emb_e, Wih_e, bih_e, genc);
  kenc2<<<1, 512, 0, stream>>>(genc, bhh_e, hseq);
  kgi<<<dim3(12, 16), 256, 0, stream>>>(target, emb_d, Wih_d, bih_d, GI);
  kwout<<<4096, 256, 0, stream>>>(Wout, WB);
  krec<<<RK, 256, 0, stream>>>(Whh_d, bhh_d, GI, hseq, cnt);
  khb<<<512, 256, 0, stream>>>(hseq, HB);
  kgemm<<<dim3((VTGT + 63) / 64, 8), 256, 0, stream>>>(HB, WB, bout, out);
  klse<<<512, 1024, 0, stream>>>(out, lse);
  ksub<<<512, 1024, 0, stream>>>(out, lse);
}

// Round 2
// 1251.465 us; speedup vs baseline: 1.6247x; 1.6247x over previous
//
#include <hip/hip_runtime.h>
#include <stdint.h>

#define HIDDEN 512
#define EMBED  256
#define VTGT   50257
#define VTGT_PAD 50304
#define TLEN   512
#define GATE3  1536
#define RK     32   // recurrence workgroups

typedef float f32x4 __attribute__((ext_vector_type(4)));
typedef unsigned int u32x4 __attribute__((ext_vector_type(4)));

__device__ __forceinline__ unsigned short f2bf(float f) {
  union { float f; unsigned u; } v; v.f = f;
  unsigned u = v.u;
  unsigned r = (u + 0x7FFFu + ((u >> 16) & 1u)) >> 16;
  return (unsigned short)r;
}

__device__ __forceinline__ float sigm(float x) {
  return 1.f / (1.f + __expf(-x));
}

// ---------- encoder: gi = Wih_e @ x_last + bih_e ----------
__global__ void kenc1(const int* source, const float* emb_e, const float* Wih_e,
                      const float* bih_e, float* genc) {
  __shared__ float xs[EMBED];
  int tid = threadIdx.x;
  int tok = source[511];
  if (tid < EMBED) xs[tid] = emb_e[(size_t)tok * EMBED + tid];
  __syncthreads();
  int j = blockIdx.x * 256 + tid;
  const float* w = Wih_e + (size_t)j * EMBED;
  float acc = bih_e[j];
  for (int k = 0; k < EMBED; k += 4) {
    float4 wv = *(const float4*)(w + k);
    acc += wv.x * xs[k] + wv.y * xs[k + 1] + wv.z * xs[k + 2] + wv.w * xs[k + 3];
  }
  genc[j] = acc;
}

// ---------- encoder gates: publish h^0 packed (tag 0); invalidate buffer 1 ----------
__global__ void kenc2(const float* genc, const float* bhh_e, unsigned long long* hpub) {
  int e = threadIdx.x; // 512 threads
  float r = sigm(genc[e] + bhh_e[e]);
  float z = sigm(genc[e + 512] + bhh_e[e + 512]);
  float n = tanhf(genc[e + 1024] + r * bhh_e[e + 1024]);
  float h = (1.f - z) * n;
  union { float f; unsigned u; } hu; hu.f = h;
  hpub[e] = (unsigned long long)hu.u;              // buffer 0, tag = 0
  hpub[HIDDEN + e] = 0xFFFFFFFF00000000ULL;        // buffer 1, invalid tag
}

// ---------- GI[t][j] = Wih_d @ relu(emb_d[tok_t]) + bih_d ----------
__global__ __launch_bounds__(256) void kgi(const int* target, const float* emb_d,
                                           const float* Wih_d, const float* bih_d,
                                           float* GI) {
  __shared__ float Xs[32][EMBED];
  int tid = threadIdx.x;
  int j0 = blockIdx.x * 128;
  int t0 = blockIdx.y * 32;
  for (int idx = tid; idx < 32 * EMBED; idx += 256) {
    int tt = idx >> 8, c = idx & 255;
    int t = t0 + tt;
    int tok = (t == 0) ? 0 : target[t - 1];
    float v = emb_d[(size_t)tok * EMBED + c];
    Xs[tt][c] = v > 0.f ? v : 0.f;
  }
  __syncthreads();
  int jl = tid & 127, tg = tid >> 7;
  int j = j0 + jl;
  const float* w = Wih_d + (size_t)j * EMBED;
  float acc[16];
#pragma unroll
  for (int i = 0; i < 16; ++i) acc[i] = 0.f;
  for (int k = 0; k < EMBED; k += 4) {
    float4 wv = *(const float4*)(w + k);
#pragma unroll
    for (int i = 0; i < 16; ++i) {
      int tl = tg * 16 + i;
      acc[i] += wv.x * Xs[tl][k] + wv.y * Xs[tl][k + 1] +
                wv.z * Xs[tl][k + 2] + wv.w * Xs[tl][k + 3];
    }
  }
  float b = bih_d[j];
#pragma unroll
  for (int i = 0; i < 16; ++i) {
    int t = t0 + tg * 16 + i;
    GI[(size_t)t * GATE3 + j] = acc[i] + b;
  }
}

// ---------- Wout f32 -> bf16 (padded rows zeroed) ----------
__global__ void kwout(const float* Wout, unsigned short* WB) {
  size_t npairs = (size_t)VTGT_PAD * HIDDEN / 2;
  size_t stride = (size_t)gridDim.x * blockDim.x;
  for (size_t p = (size_t)blockIdx.x * blockDim.x + threadIdx.x; p < npairs; p += stride) {
    size_t i = p * 2;
    int j = (int)(i / HIDDEN);
    float a = 0.f, b = 0.f;
    if (j < VTGT) { float2 v = *(const float2*)(Wout + i); a = v.x; b = v.y; }
    *(unsigned*)(WB + i) = (unsigned)f2bf(a) | ((unsigned)f2bf(b) << 16);
  }
}

// ---------- sequential GRU recurrence, 32 persistent WGs, packed (val,tag) flow ----------
__global__ __launch_bounds__(256) void krec(const float* Whh, const float* bhh,
                                            const float* GI,
                                            unsigned long long* hpub,
                                            unsigned short* HB) {
  int tid = threadIdx.x;
  int p = tid & 15;            // k-slice owner
  int eg = tid >> 4;           // 0..15
  int e = blockIdx.x * 16 + eg;
  int k0 = p * 32;
  // persistent weights in VGPRs: rows e, e+512, e+1024, cols k0..k0+31
  float wr[32], wz[32], wn[32];
  {
    const float* Wr = Whh + (size_t)e * HIDDEN + k0;
    const float* Wz = Whh + (size_t)(e + 512) * HIDDEN + k0;
    const float* Wn = Whh + (size_t)(e + 1024) * HIDDEN + k0;
#pragma unroll
    for (int i = 0; i < 32; i += 4) {
      *(float4*)&wr[i] = *(const float4*)(Wr + i);
      *(float4*)&wz[i] = *(const float4*)(Wz + i);
      *(float4*)&wn[i] = *(const float4*)(Wn + i);
    }
  }
  float br = bhh[e], bz = bhh[e + 512], bn = bhh[e + 1024];
  __shared__ float hb[16 * 36];   // padded stride 36
  int g0 = tid * 2, g1 = g0 + 1;
  int hb0 = ((g0 >> 5) * 36) + (g0 & 31);
  int hb1 = ((g1 >> 5) * 36) + (g1 & 31);
  int hb_e = ((e >> 5) * 36) + (e & 31);
  for (int t = 0; t < TLEN; ++t) {
    // prefetch GI for this step (independent of h -> hides under the poll)
    float gie = 0.f, giz = 0.f, gin = 0.f;
    if (p == 0) {
      const float* git = GI + (size_t)t * GATE3;
      gie = git[e]; giz = git[e + 512]; gin = git[e + 1024];
    }
    // consume h^t: spin directly on packed (value, tag) words
    unsigned long long* buf = hpub + (size_t)(t & 1) * HIDDEN;
    unsigned want = (unsigned)t;
    unsigned long long v0, v1;
    do {
      v0 = __hip_atomic_load(buf + g0, __ATOMIC_RELAXED, __HIP_MEMORY_SCOPE_AGENT);
    } while ((unsigned)(v0 >> 32) != want);
    do {
      v1 = __hip_atomic_load(buf + g1, __ATOMIC_RELAXED, __HIP_MEMORY_SCOPE_AGENT);
    } while ((unsigned)(v1 >> 32) != want);
    union { unsigned u; float f; } c0, c1;
    c0.u = (unsigned)v0; c1.u = (unsigned)v1;
    hb[hb0] = c0.f;
    hb[hb1] = c1.f;
    __syncthreads();
    float pr = 0.f, pz = 0.f, pn = 0.f;
#pragma unroll
    for (int i = 0; i < 32; i += 4) {
      float4 hv = *(float4*)&hb[p * 36 + i];
      pr += wr[i] * hv.x + wr[i + 1] * hv.y + wr[i + 2] * hv.z + wr[i + 3] * hv.w;
      pz += wz[i] * hv.x + wz[i + 1] * hv.y + wz[i + 2] * hv.z + wz[i + 3] * hv.w;
      pn += wn[i] * hv.x + wn[i + 1] * hv.y + wn[i + 2] * hv.z + wn[i + 3] * hv.w;
    }
#pragma unroll
    for (int m = 1; m < 16; m <<= 1) {
      pr += __shfl_xor(pr, m, 64);
      pz += __shfl_xor(pz, m, 64);
      pn += __shfl_xor(pn, m, 64);
    }
    if (p == 0) {
      float r = sigm(gie + pr + br);
      float z = sigm(giz + pz + bz);
      float n = tanhf(gin + r * (pn + bn));
      float hold = hb[hb_e];
      float hnew = (1.f - z) * n + z * hold;
      HB[(size_t)t * HIDDEN + e] = f2bf(hnew);   // bf16 row for the GEMM
      union { float f; unsigned u; } hu; hu.f = hnew;
      unsigned long long pk = (unsigned long long)hu.u |
                              ((unsigned long long)(unsigned)(t + 1) << 32);
      __hip_atomic_store(hpub + (size_t)((t + 1) & 1) * HIDDEN + e, pk,
                         __ATOMIC_RELAXED, __HIP_MEMORY_SCOPE_AGENT);
    }
    __syncthreads();   // nobody rewrites hb before all dots of step t are done
  }
}

// ---------- logits = HB @ WB^T + bout  (bf16 MFMA) ----------
__global__ __launch_bounds__(256) void kgemm(const unsigned short* HB,
                                             const unsigned short* WB,
                                             const float* bout, float* out) {
  __shared__ unsigned short As[64 * 264]; // 64 rows x (256+8 pad) bf16, per K-half
  int tid = threadIdx.x;
  int lane = tid & 63, w = tid >> 6;
  int j0 = blockIdx.x * 64;
  int t0 = blockIdx.y * 64;
  int jl = lane & 15, kq = lane >> 4;
  int j = j0 + w * 16 + jl;
  f32x4 acc[4];
#pragma unroll
  for (int i = 0; i < 4; ++i) acc[i] = (f32x4)(0.f);
  for (int kh = 0; kh < 2; ++kh) {
    __syncthreads();
#pragma unroll
    for (int i = 0; i < 8; ++i) {
      int c = tid + 256 * i;
      int row = c >> 5, off = (c & 31) * 8;
      u32x4 v = *(const u32x4*)(HB + (size_t)(t0 + row) * HIDDEN + kh * 256 + off);
      *(u32x4*)(As + row * 264 + off) = v;
    }
    __syncthreads();
    const unsigned short* Bp = WB + (size_t)j * HIDDEN + kh * 256 + kq * 8;
#pragma unroll
    for (int ks = 0; ks < 8; ++ks) {
      u32x4 bfrag = *(const u32x4*)(Bp + ks * 32);
#pragma unroll
      for (int tq = 0; tq < 4; ++tq) {
        u32x4 afrag = *(const u32x4*)(As + (tq * 16 + jl) * 264 + ks * 32 + kq * 8);
        asm volatile("v_mfma_f32_16x16x32_bf16 %0, %1, %2, %0"
                     : "+v"(acc[tq])
                     : "v"(afrag), "v"(bfrag));
      }
    }
  }
  asm volatile("s_nop 7\n\ts_nop 7\n\ts_nop 7" ::);
  bool jok = j < VTGT;
  float bj = jok ? bout[j] : 0.f;
#pragma unroll
  for (int tq = 0; tq < 4; ++tq) {
#pragma unroll
    for (int r = 0; r < 4; ++r) {
      int t = t0 + tq * 16 + kq * 4 + r;   // D: row=(lane>>4)*4+reg, col=lane&15
      if (jok) out[(size_t)t * VTGT + j] = acc[tq][r] + bj;
    }
  }
}

// ---------- per-row logsumexp over d_out ----------
__global__ void klse(const float* out, float* lse) {
  int t = blockIdx.x, tid = threadIdx.x;
  const float* row = out + (size_t)t * VTGT;
  float m = -INFINITY, s = 0.f;
  for (int jj = tid; jj < VTGT; jj += 1024) {
    float x = row[jj];
    if (x > m) { s = s * __expf(m - x) + 1.f; m = x; }
    else s += __expf(x - m);
  }
#pragma unroll
  for (int d = 1; d < 64; d <<= 1) {
    float mo = __shfl_xor(m, d, 64), so = __shfl_xor(s, d, 64);
    float mn = fmaxf(m, mo);
    s = s * __expf(m - mn) + so * __expf(mo - mn);
    m = mn;
  }
  __shared__ float sm[16], sv[16];
  if ((tid & 63) == 0) { sm[tid >> 6] = m; sv[tid >> 6] = s; }
  __syncthreads();
  if (tid == 0) {
    for (int q = 1; q < 16; ++q) {
      float mo = sm[q], so = sv[q];
      float mn = fmaxf(m, mo);
      s = s * __expf(m - mn) + so * __expf(mo - mn);
      m = mn;
    }
    lse[t] = m + logf(s);
  }
}

// ---------- logp = logits - lse[t], in place ----------
__global__ void ksub(float* out, const float* lse) {
  int t = blockIdx.x;
  float l = lse[t];
  float* row = out + (size_t)t * VTGT;
  for (int jj = threadIdx.x; jj < VTGT; jj += 1024) row[jj] -= l;
}

extern "C" void kernel_launch(void* const* d_in, const int* in_sizes, int n_in,
                              void* d_out, int out_size, void* d_ws, size_t ws_size,
                              hipStream_t stream) {
  const int*   source = (const int*)d_in[0];
  const int*   target = (const int*)d_in[1];
  const float* emb_e  = (const float*)d_in[2];
  const float* Wih_e  = (const float*)d_in[3];
  // d_in[4] = Whh_e: unused (h0 == 0)
  const float* bih_e  = (const float*)d_in[5];
  const float* bhh_e  = (const float*)d_in[6];
  const float* emb_d  = (const float*)d_in[7];
  const float* Wih_d  = (const float*)d_in[8];
  const float* Whh_d  = (const float*)d_in[9];
  const float* bih_d  = (const float*)d_in[10];
  const float* bhh_d  = (const float*)d_in[11];
  const float* Wout   = (const float*)d_in[12];
  const float* bout   = (const float*)d_in[13];
  float* out = (float*)d_out;
  char* ws = (char*)d_ws;

  // ws layout (bytes), all offsets 256-aligned
  float*              GI   = (float*)(ws + 0);            // 3,145,728
  unsigned long long* hpub = (unsigned long long*)(ws + 3145728); // 8,192 (2 x 512 x 8B)
  float*              lse  = (float*)(ws + 3153920);      //     2,048
  float*              genc = (float*)(ws + 3155968);      //     6,144
  unsigned short*     WB   = (unsigned short*)(ws + 3162112);   // 51,511,296
  unsigned short*     HB   = (unsigned short*)(ws + 54673408);  //   524,288
  // total ws use ~55.2 MB

  kenc1<<<6, 256, 0, stream>>>(source, emb_e, Wih_e, bih_e, genc);
  kenc2<<<1, 512, 0, stream>>>(genc, bhh_e, hpub);
  kgi<<<dim3(12, 16), 256, 0, stream>>>(target, emb_d, Wih_d, bih_d, GI);
  kwout<<<4096, 256, 0, stream>>>(Wout, WB);
  krec<<<RK, 256, 0, stream>>>(Whh_d, bhh_d, GI, hpub, HB);
  kgemm<<<dim3((VTGT + 63) / 64, 8), 256, 0, stream>>>(HB, WB, bout, out);
  klse<<<512, 1024, 0, stream>>>(out, lse);
  ksub<<<512, 1024, 0, stream>>>(out, lse);
}